// Round 6
// baseline (1599.200 us; speedup 1.0000x reference)
//
#include <hip/hip_runtime.h>

#define LL 12
#define NN 2048
#define KK 8
#define SS 4
#define HH 256
#define LN (LL*NN)
#define VV 50000
#define NB 256

typedef __bf16 bf16_t;
typedef __bf16 bf16x8 __attribute__((ext_vector_type(8)));
typedef __bf16 bf16x4v __attribute__((ext_vector_type(4)));
typedef float f32x4 __attribute__((ext_vector_type(4)));

__device__ __forceinline__ float sigmoidf_(float x) { return 1.f / (1.f + expf(-x)); }

// ---------------- E f32 -> bf16 ----------------
__global__ __launch_bounds__(256) void k_cvtE(const float* __restrict__ src,
                                              bf16_t* __restrict__ dst, int n4)
{
    int i = blockIdx.x * 256 + threadIdx.x;
    const int stride = gridDim.x * 256;
    for (; i < n4; i += stride) {
        const float4 v = ((const float4*)src)[i];
        bf16x4v o;
        o[0] = (bf16_t)v.x; o[1] = (bf16_t)v.y; o[2] = (bf16_t)v.z; o[3] = (bf16_t)v.w;
        ((bf16x4v*)dst)[i] = o;
    }
}

// ---------------- weight transposes + barrier-counter zero ----------------
__global__ __launch_bounds__(256) void k_cvtW(
    const float* __restrict__ linW, const float* __restrict__ WW,
    const float* __restrict__ UfW, const float* __restrict__ UiW,
    bf16_t* __restrict__ linWt, bf16_t* __restrict__ WWt,
    bf16_t* __restrict__ UfWt, bf16_t* __restrict__ UiWt,
    unsigned* __restrict__ cnt)
{
    if (blockIdx.x == 0 && threadIdx.x == 0) *cnt = 0u;
    int i = blockIdx.x * 256 + threadIdx.x;      // total 786432
    if (i < 262144) {                            // linW (1024,256) -> (256,1024)
        const int rr = i >> 8, cc = i & 255;
        linWt[(size_t)cc * 1024 + rr] = (bf16_t)linW[i];
        return;
    }
    i -= 262144;
    if (i < 262144) {                            // WW (256,1024) -> (1024,256)
        const int rr = i >> 10, cc = i & 1023;
        WWt[(size_t)cc * 256 + rr] = (bf16_t)WW[i];
        return;
    }
    i -= 262144;
    if (i < 65536) {                             // UfW (256,256) -> (256,256)
        const int rr = i >> 8, cc = i & 255;
        UfWt[(size_t)cc * 256 + rr] = (bf16_t)UfW[i];
        return;
    }
    i -= 65536;
    if (i < 196608) {                            // UiW (256,768) -> (768,256)
        const int rr = i / 768, cc = i - rr * 768;
        UiWt[(size_t)cc * 256 + rr] = (bf16_t)UiW[i];
    }
}

// ---------------- embed GEMM: x = concat_s(Ebf[tok_s]) @ lin_W + lin_b ----------------
// 1536 blocks x 256 thr (4 waves, col-split); block tile 32x256, wave tile 32x64.
__global__ __launch_bounds__(256) void k_embed(
    const int* __restrict__ tok1, const int* __restrict__ tok2,
    const bf16_t* __restrict__ Ebf, const bf16_t* __restrict__ linWt,
    const float* __restrict__ linb, bf16_t* __restrict__ xout)
{
    __shared__ int toff[32][SS];
    const int t = threadIdx.x;
    const int m0 = blockIdx.x * 32;
    if (t < 128) {
        const int lr = t >> 2, s = t & 3;
        const int m = m0 + lr;
        const int e = (m >= LN) ? 1 : 0;
        const int rrow = m - e * LN;
        const int* tok = e ? tok2 : tok1;
        toff[lr][s] = tok[(size_t)rrow * SS + s] * HH;
    }
    __syncthreads();
    const int lane = t & 63, w = t >> 6;
    const int r = lane & 15, kg = lane >> 4;
    const bf16_t* bp[4];
    #pragma unroll
    for (int j = 0; j < 4; ++j)
        bp[j] = linWt + (size_t)(w * 64 + j * 16 + r) * 1024 + kg * 8;

    const f32x4 zero = {0.f, 0.f, 0.f, 0.f};
    f32x4 acc[2][4];
    #pragma unroll
    for (int mi = 0; mi < 2; ++mi)
        #pragma unroll
        for (int j = 0; j < 4; ++j) acc[mi][j] = zero;

    const int koff = kg * 8;
    for (int k0 = 0; k0 < 1024; k0 += 32) {
        const int s = k0 >> 8, off = (k0 & 255) + koff;
        const bf16x8 a0 = *(const bf16x8*)(Ebf + (size_t)toff[r][s] + off);
        const bf16x8 a1 = *(const bf16x8*)(Ebf + (size_t)toff[r + 16][s] + off);
        #pragma unroll
        for (int j = 0; j < 4; ++j) {
            const bf16x8 b = *(const bf16x8*)bp[j];
            acc[0][j] = __builtin_amdgcn_mfma_f32_16x16x32_bf16(a0, b, acc[0][j], 0, 0, 0);
            acc[1][j] = __builtin_amdgcn_mfma_f32_16x16x32_bf16(a1, b, acc[1][j], 0, 0, 0);
            bp[j] += 32;
        }
    }
    #pragma unroll
    for (int j = 0; j < 4; ++j) {
        const int ccol = w * 64 + j * 16 + r;
        const float bv = linb[ccol];
        #pragma unroll
        for (int mi = 0; mi < 2; ++mi)
            #pragma unroll
            for (int jj = 0; jj < 4; ++jj)
                xout[(size_t)(m0 + mi * 16 + kg * 4 + jj) * HH + ccol] =
                    (bf16_t)(acc[mi][j][jj] + bv);
    }
}

// ---------------- persistent scan kernel: all 12 steps, 1 grid barrier per step ----------------
// 256 blocks x 512 thr (8 waves), 16 rows/block; LDS ~65 KB; VGPR capped 128 -> 2 blocks/CU
// capacity, so all 256 blocks are guaranteed resident (no deadlock).
__global__ __launch_bounds__(512, 4) void k_scan(
    const bf16_t* __restrict__ xbf,
    const int* __restrict__ idx1, const int* __restrict__ idx2,
    const bf16_t* __restrict__ UfWt, const float* __restrict__ Ufb,
    const bf16_t* __restrict__ UiWt, const float* __restrict__ Uib,
    const bf16_t* __restrict__ WWt, const float* __restrict__ Wb,
    bf16_t* __restrict__ hA, bf16_t* __restrict__ hB,
    float* __restrict__ cA, float* __restrict__ cB,
    bf16_t* __restrict__ HfA, bf16_t* __restrict__ HfB,
    unsigned* __restrict__ cnt)
{
    __shared__ __align__(16) bf16_t sh[16 * 256];     // hsum (ph1-2) then h_next (ph3-4), swizzled
    __shared__ __align__(16) bf16_t WxL[16 * 1024];   // 32 KB
    __shared__ __align__(16) bf16_t iuoL[16 * 768];   // 24 KB
    __shared__ int childL[16][KK];

    const int t = threadIdx.x;
    const int g0 = blockIdx.x * 16;
    const int e  = g0 >> 11;
    const int n0 = g0 & (NN - 1);
    const int* idxbase = e ? idx2 : idx1;
    const int lane = t & 63, w = t >> 6;
    const int r = lane & 15, kg = lane >> 4;
    const f32x4 zero = {0.f, 0.f, 0.f, 0.f};

    for (int l = 0; l < LL; ++l) {
        const bf16_t* hprev  = (l & 1) ? hB : hA;
        bf16_t*       hnext  = (l & 1) ? hA : hB;
        const float*  cprev  = (l & 1) ? cB : cA;
        float*        cnextp = (l & 1) ? cA : cB;
        const bf16_t* HfPrev = (l & 1) ? HfB : HfA;
        bf16_t*       HfNext = (l & 1) ? HfA : HfB;
        const int* idxp = idxbase + ((size_t)l * NN + n0) * KK;

        // ---- phase 0: child ids + prefetch Wx A-rows into registers ----
        if (t < 128) {
            const int rr = t >> 3, k = t & 7;
            const int il = idxp[rr * KK + k];
            childL[rr][k] = (il >= 1) ? (e * NN + il - 1) : -1;
        }
        const bf16_t* xrow = xbf + ((size_t)e * LN + (size_t)l * NN + n0 + r) * HH + kg * 8;
        bf16x8 aWx[8];
        #pragma unroll
        for (int k = 0; k < 8; ++k) aWx[k] = *(const bf16x8*)(xrow + k * 32);
        __syncthreads();

        // ---- phase 1: hsum gather (16 rows x 32 slices of 16B) ----
        {
            const int rr = t >> 5, c8 = t & 31;
            float acc[8] = {0.f, 0.f, 0.f, 0.f, 0.f, 0.f, 0.f, 0.f};
            #pragma unroll
            for (int k = 0; k < KK; ++k) {
                const int ch = childL[rr][k];
                if (ch >= 0) {
                    const bf16x8 v = *(const bf16x8*)(hprev + (size_t)ch * HH + c8 * 8);
                    #pragma unroll
                    for (int jj = 0; jj < 8; ++jj) acc[jj] += (float)v[jj];
                }
            }
            bf16x8 o;
            #pragma unroll
            for (int jj = 0; jj < 8; ++jj) o[jj] = (bf16_t)acc[jj];
            const int ss = (c8 + 4 * (rr & 7)) & 31;
            *(bf16x8*)(sh + rr * 256 + ss * 8) = o;
        }
        __syncthreads();

        // ---- phase 2a: Wx = x_l @ WW + Wb  (wave w -> col tiles 8w..8w+7) ----
        {
            const bf16_t* bw[8];
            #pragma unroll
            for (int j = 0; j < 8; ++j)
                bw[j] = WWt + (size_t)((8 * w + j) * 16 + r) * HH + kg * 8;
            f32x4 acc[8];
            #pragma unroll
            for (int j = 0; j < 8; ++j) acc[j] = zero;
            #pragma unroll
            for (int k = 0; k < 8; ++k) {
                #pragma unroll
                for (int j = 0; j < 8; ++j) {
                    const bf16x8 b = *(const bf16x8*)bw[j];
                    acc[j] = __builtin_amdgcn_mfma_f32_16x16x32_bf16(aWx[k], b, acc[j], 0, 0, 0);
                    bw[j] += 32;
                }
            }
            #pragma unroll
            for (int j = 0; j < 8; ++j) {
                const int col = (8 * w + j) * 16 + r;
                const float bv = Wb[col];
                #pragma unroll
                for (int jj = 0; jj < 4; ++jj)
                    WxL[(size_t)(kg * 4 + jj) * 1024 + col] = (bf16_t)(acc[j][jj] + bv);
            }
        }
        // ---- phase 2b: iuo = hsum @ UiW + Uib  (wave w -> col tiles 6w..6w+5) ----
        {
            const bf16_t* bu[6];
            #pragma unroll
            for (int j = 0; j < 6; ++j)
                bu[j] = UiWt + (size_t)((6 * w + j) * 16 + r) * HH + kg * 8;
            f32x4 acc[6];
            #pragma unroll
            for (int j = 0; j < 6; ++j) acc[j] = zero;
            for (int k0 = 0; k0 < HH; k0 += 32) {
                const int ss = (((k0 >> 3) + kg) + 4 * (r & 7)) & 31;
                const bf16x8 a = *(const bf16x8*)(sh + r * 256 + ss * 8);
                #pragma unroll
                for (int j = 0; j < 6; ++j) {
                    const bf16x8 b = *(const bf16x8*)bu[j];
                    acc[j] = __builtin_amdgcn_mfma_f32_16x16x32_bf16(a, b, acc[j], 0, 0, 0);
                    bu[j] += 32;
                }
            }
            #pragma unroll
            for (int j = 0; j < 6; ++j) {
                const int col = (6 * w + j) * 16 + r;
                const float bv = Uib[col];
                #pragma unroll
                for (int jj = 0; jj < 4; ++jj)
                    iuoL[(size_t)(kg * 4 + jj) * 768 + col] = (bf16_t)(acc[j][jj] + bv);
            }
        }
        __syncthreads();

        // ---- phase 3: gates (gather HfPrev/cprev; write h/c global + h_next to sh) ----
        {
            const int col = t & 255, rb2 = t >> 8;
            for (int i = 0; i < 8; ++i) {
                const int rr = i * 2 + rb2;
                const int g = g0 + rr;
                const float Wf = (float)WxL[(size_t)rr * 1024 + col];
                const float Wi = (float)WxL[(size_t)rr * 1024 + 256 + col];
                const float Wu = (float)WxL[(size_t)rr * 1024 + 512 + col];
                const float Wo = (float)WxL[(size_t)rr * 1024 + 768 + col];
                float bfa = 0.f;
                #pragma unroll
                for (int k = 0; k < KK; ++k) {
                    const int ch = childL[rr][k];
                    if (ch >= 0) {
                        const float hf = (float)HfPrev[(size_t)ch * HH + col];
                        const float fk = sigmoidf_(Wf + hf);
                        bfa = fmaf(fk, cprev[(size_t)ch * HH + col], bfa);
                    }
                }
                const float ig = sigmoidf_((float)iuoL[(size_t)rr * 768 + col] + Wi);
                const float ug = tanhf((float)iuoL[(size_t)rr * 768 + 256 + col] + Wu);
                const float og = sigmoidf_((float)iuoL[(size_t)rr * 768 + 512 + col] + Wo);
                const float nc = fmaf(ig, ug, bfa);
                const float nh = og * tanhf(nc);
                cnextp[(size_t)g * HH + col] = nc;
                const bf16_t nhb = (bf16_t)nh;
                hnext[(size_t)g * HH + col] = nhb;
                const int ss = ((col >> 3) + 4 * (rr & 7)) & 31;
                sh[rr * 256 + ss * 8 + (col & 7)] = nhb;
            }
        }

        if (l < LL - 1) {
            __syncthreads();
            // ---- phase 4: Hf_next = h_next @ UfW + Ufb (own 16 rows; wave w -> tiles 2w,2w+1) ----
            {
                const int ct0 = 2 * w;
                const bf16_t* bq0 = UfWt + (size_t)(ct0 * 16 + r) * HH + kg * 8;
                const bf16_t* bq1 = bq0 + (size_t)16 * HH;
                f32x4 ac0 = zero, ac1 = zero;
                for (int k0 = 0; k0 < HH; k0 += 32) {
                    const int ss = (((k0 >> 3) + kg) + 4 * (r & 7)) & 31;
                    const bf16x8 a = *(const bf16x8*)(sh + r * 256 + ss * 8);
                    const bf16x8 b0 = *(const bf16x8*)bq0;
                    const bf16x8 b1 = *(const bf16x8*)bq1;
                    ac0 = __builtin_amdgcn_mfma_f32_16x16x32_bf16(a, b0, ac0, 0, 0, 0);
                    ac1 = __builtin_amdgcn_mfma_f32_16x16x32_bf16(a, b1, ac1, 0, 0, 0);
                    bq0 += 32; bq1 += 32;
                }
                const int c0 = ct0 * 16 + r, c1 = c0 + 16;
                const float bv0 = Ufb[c0], bv1 = Ufb[c1];
                #pragma unroll
                for (int jj = 0; jj < 4; ++jj) {
                    HfNext[(size_t)(g0 + kg * 4 + jj) * HH + c0] = (bf16_t)(ac0[jj] + bv0);
                    HfNext[(size_t)(g0 + kg * 4 + jj) * HH + c1] = (bf16_t)(ac1[jj] + bv1);
                }
            }
            // ---- grid barrier (device-scope) ----
            __syncthreads();
            if (t == 0) {
                __threadfence();
                __hip_atomic_fetch_add(cnt, 1u, __ATOMIC_RELAXED, __HIP_MEMORY_SCOPE_AGENT);
                const unsigned target = (unsigned)NB * (unsigned)(l + 1);
                while (__hip_atomic_load(cnt, __ATOMIC_RELAXED, __HIP_MEMORY_SCOPE_AGENT) < target)
                    __builtin_amdgcn_s_sleep(2);
                __threadfence();
            }
            __syncthreads();
        }
    }
}

// ---------------- siamese head ----------------
__global__ __launch_bounds__(256) void k_final(
    const bf16_t* __restrict__ hlast, const bf16_t* __restrict__ xbf,
    const float* __restrict__ dW, const float* __restrict__ db,
    const float* __restrict__ oW, const float* __restrict__ ob,
    float* __restrict__ out)
{
    __shared__ __align__(16) float ad[8][HH];
    __shared__ __align__(16) float xx[8][512];
    const int t = threadIdx.x;
    const int n0 = blockIdx.x * 8;
    const size_t xoff1 = (size_t)(LL - 1) * NN * HH;
    const size_t xoff2 = (size_t)LN * HH + xoff1;
    #pragma unroll
    for (int rr = 0; rr < 8; ++rr) {
        const int n = n0 + rr;
        const float h1 = (float)hlast[(size_t)n * HH + t] + (float)xbf[xoff1 + (size_t)n * HH + t];
        const float h2 = (float)hlast[((size_t)NN + n) * HH + t] + (float)xbf[xoff2 + (size_t)n * HH + t];
        ad[rr][t] = fabsf(h1 - h2);
    }
    __syncthreads();
    float a0[8], a1[8];
    #pragma unroll
    for (int rr = 0; rr < 8; ++rr) { a0[rr] = 0.f; a1[rr] = 0.f; }
    for (int k = 0; k < HH; k += 4) {
        #pragma unroll
        for (int kk = 0; kk < 4; ++kk) {
            const float b0 = dW[(size_t)(k + kk) * 512 + t];
            const float b1 = dW[(size_t)(k + kk) * 512 + 256 + t];
            #pragma unroll
            for (int rr = 0; rr < 8; ++rr) {
                const float av = ad[rr][k + kk];
                a0[rr] = fmaf(av, b0, a0[rr]);
                a1[rr] = fmaf(av, b1, a1[rr]);
            }
        }
    }
    const float db0 = db[t], db1 = db[256 + t];
    #pragma unroll
    for (int rr = 0; rr < 8; ++rr) {
        xx[rr][t] = tanhf(a0[rr] + db0);
        xx[rr][256 + t] = tanhf(a1[rr] + db1);
    }
    __syncthreads();
    const int w = t >> 6, lane = t & 63;
    for (int rr = w; rr < 8; rr += 4) {
        float p0 = 0.f, p1 = 0.f;
        for (int k = lane; k < 512; k += 64) {
            const float xv = xx[rr][k];
            p0 = fmaf(xv, oW[2 * k + 0], p0);
            p1 = fmaf(xv, oW[2 * k + 1], p1);
        }
        #pragma unroll
        for (int off = 32; off > 0; off >>= 1) {
            p0 += __shfl_down(p0, off);
            p1 += __shfl_down(p1, off);
        }
        if (lane == 0) {
            const float l0 = p0 + ob[0], l1 = p1 + ob[1];
            const float mx = fmaxf(l0, l1);
            const float e0 = expf(l0 - mx), e1 = expf(l1 - mx);
            const float inv = 1.f / (e0 + e1);
            out[(size_t)(n0 + rr) * 2 + 0] = e0 * inv;
            out[(size_t)(n0 + rr) * 2 + 1] = e1 * inv;
        }
    }
}

extern "C" void kernel_launch(void* const* d_in, const int* in_sizes, int n_in,
                              void* d_out, int out_size, void* d_ws, size_t ws_size,
                              hipStream_t stream) {
    (void)in_sizes; (void)n_in; (void)out_size; (void)ws_size;
    const int*   tok1 = (const int*)d_in[0];
    const int*   idx1 = (const int*)d_in[1];
    const int*   tok2 = (const int*)d_in[2];
    const int*   idx2 = (const int*)d_in[3];
    const float* E    = (const float*)d_in[4];
    const float* linW = (const float*)d_in[5];
    const float* linb = (const float*)d_in[6];
    const float* UfW  = (const float*)d_in[7];
    const float* Ufb  = (const float*)d_in[8];
    const float* UiW  = (const float*)d_in[9];
    const float* Uib  = (const float*)d_in[10];
    const float* WW   = (const float*)d_in[11];
    const float* Wb   = (const float*)d_in[12];
    const float* dW   = (const float*)d_in[13];
    const float* db   = (const float*)d_in[14];
    const float* oW   = (const float*)d_in[15];
    const float* ob   = (const float*)d_in[16];
    float* out = (float*)d_out;

    // ws: xbf | UNION{ Ebf (dead after embed) | hA hB HfA HfB cA cB } | weights | cnt  (~52.3 MB)
    bf16_t* xbf = (bf16_t*)d_ws;                        // 12,582,912 elems
    char*   uni = (char*)(xbf + (size_t)12582912);
    bf16_t* Ebf = (bf16_t*)uni;                         // 12,800,000 elems (25.6 MB)
    bf16_t* hA  = (bf16_t*)uni;                         // 1,048,576 each below
    bf16_t* hB  = hA  + (size_t)1048576;
    bf16_t* HfA = hB  + (size_t)1048576;
    bf16_t* HfB = HfA + (size_t)1048576;
    float*  cA  = (float*)(HfB + (size_t)1048576);
    float*  cB  = cA + (size_t)1048576;                 // step bufs total 16 MB < 25.6 MB
    bf16_t* linWt = (bf16_t*)(uni + 25600000);          // 262,144
    bf16_t* WWt   = linWt + (size_t)262144;             // 262,144
    bf16_t* UfWt  = WWt   + (size_t)262144;             // 65,536
    bf16_t* UiWt  = UfWt  + (size_t)65536;              // 196,608
    unsigned* cnt = (unsigned*)(UiWt + (size_t)196608);

    k_cvtE<<<2048, 256, 0, stream>>>(E, Ebf, VV * HH / 4);
    k_cvtW<<<3072, 256, 0, stream>>>(linW, WW, UfW, UiW, linWt, WWt, UfWt, UiWt, cnt);

    k_embed<<<1536, 256, 0, stream>>>(tok1, tok2, Ebf, linWt, linb, xbf);

    k_scan<<<NB, 512, 0, stream>>>(xbf, idx1, idx2, UfWt, Ufb, UiWt, Uib, WWt, Wb,
                                   hA, hB, cA, cB, HfA, HfB, cnt);

    // after 12 steps, last h is in hA (l=11 writes hnext=hA)
    k_final<<<NN / 8, 256, 0, stream>>>(hA, xbf, dW, db, oW, ob, out);
}

// Round 7
// 1322.172 us; speedup vs baseline: 1.2095x; 1.2095x over previous
//
#include <hip/hip_runtime.h>

#define LL 12
#define NN 2048
#define KK 8
#define SS 4
#define HH 256
#define LN (LL*NN)
#define VV 50000

typedef __bf16 bf16_t;
typedef __bf16 bf16x8 __attribute__((ext_vector_type(8)));
typedef __bf16 bf16x4v __attribute__((ext_vector_type(4)));
typedef float f32x4 __attribute__((ext_vector_type(4)));

__device__ __forceinline__ float sigmoidf_(float x) { return 1.f / (1.f + expf(-x)); }

// ---------------- E f32 -> bf16 ----------------
__global__ __launch_bounds__(256) void k_cvtE(const float* __restrict__ src,
                                              bf16_t* __restrict__ dst, int n4)
{
    int i = blockIdx.x * 256 + threadIdx.x;
    const int stride = gridDim.x * 256;
    for (; i < n4; i += stride) {
        const float4 v = ((const float4*)src)[i];
        bf16x4v o;
        o[0] = (bf16_t)v.x; o[1] = (bf16_t)v.y; o[2] = (bf16_t)v.z; o[3] = (bf16_t)v.w;
        ((bf16x4v*)dst)[i] = o;
    }
}

// ---------------- weight transposes (f32 (K,N) -> bf16 (N,K)) ----------------
__global__ __launch_bounds__(256) void k_cvtW(
    const float* __restrict__ linW, const float* __restrict__ WW,
    const float* __restrict__ UfW, const float* __restrict__ UiW,
    bf16_t* __restrict__ linWt, bf16_t* __restrict__ WWt,
    bf16_t* __restrict__ UfWt, bf16_t* __restrict__ UiWt)
{
    int i = blockIdx.x * 256 + threadIdx.x;      // total 786432
    if (i < 262144) {                            // linW (1024,256) -> (256,1024)
        const int rr = i >> 8, cc = i & 255;
        linWt[(size_t)cc * 1024 + rr] = (bf16_t)linW[i];
        return;
    }
    i -= 262144;
    if (i < 262144) {                            // WW (256,1024) -> (1024,256)
        const int rr = i >> 10, cc = i & 1023;
        WWt[(size_t)cc * 256 + rr] = (bf16_t)WW[i];
        return;
    }
    i -= 262144;
    if (i < 65536) {                             // UfW (256,256) -> (256,256)
        const int rr = i >> 8, cc = i & 255;
        UfWt[(size_t)cc * 256 + rr] = (bf16_t)UfW[i];
        return;
    }
    i -= 65536;
    if (i < 196608) {                            // UiW (256,768) -> (768,256)
        const int rr = i / 768, cc = i - rr * 768;
        UiWt[(size_t)cc * 256 + rr] = (bf16_t)UiW[i];
    }
}

// ---------------- embed GEMM (round-3 measured-best): 768 blocks x 256 thr ----------------
__global__ __launch_bounds__(256) void k_embed(
    const int* __restrict__ tok1, const int* __restrict__ tok2,
    const bf16_t* __restrict__ Ebf, const bf16_t* __restrict__ linWt,
    const float* __restrict__ linb, bf16_t* __restrict__ xout)
{
    __shared__ int toff[64][SS];
    const int t = threadIdx.x;
    const int m0 = blockIdx.x * 64;
    {
        const int lr = t >> 2, s = t & 3;
        const int m = m0 + lr;
        const int e = (m >= LN) ? 1 : 0;
        const int rrow = m - e * LN;
        const int* tok = e ? tok2 : tok1;
        toff[lr][s] = tok[(size_t)rrow * SS + s] * HH;
    }
    __syncthreads();
    const int lane = t & 63, w = t >> 6;
    const int wm = w >> 1, wn = w & 1;
    const int r = lane & 15, kg = lane >> 4;
    const int lr0 = wm * 32 + r, lr1 = lr0 + 16;
    const bf16_t* bp[8];
    #pragma unroll
    for (int j = 0; j < 8; ++j)
        bp[j] = linWt + (size_t)(wn * 128 + j * 16 + r) * 1024 + kg * 8;

    const f32x4 zero = {0.f, 0.f, 0.f, 0.f};
    f32x4 acc[2][8];
    #pragma unroll
    for (int mi = 0; mi < 2; ++mi)
        #pragma unroll
        for (int j = 0; j < 8; ++j) acc[mi][j] = zero;

    for (int k0 = 0; k0 < 1024; k0 += 32) {
        const int s = k0 >> 8, off = (k0 & 255) + kg * 8;
        const bf16x8 a0 = *(const bf16x8*)(Ebf + (size_t)toff[lr0][s] + off);
        const bf16x8 a1 = *(const bf16x8*)(Ebf + (size_t)toff[lr1][s] + off);
        #pragma unroll
        for (int j = 0; j < 8; ++j) {
            const bf16x8 b = *(const bf16x8*)bp[j];
            acc[0][j] = __builtin_amdgcn_mfma_f32_16x16x32_bf16(a0, b, acc[0][j], 0, 0, 0);
            acc[1][j] = __builtin_amdgcn_mfma_f32_16x16x32_bf16(a1, b, acc[1][j], 0, 0, 0);
            bp[j] += 32;
        }
    }
    const int crow = m0 + wm * 32 + kg * 4;
    #pragma unroll
    for (int j = 0; j < 8; ++j) {
        const int ccol = wn * 128 + j * 16 + r;
        const float bv = linb[ccol];
        #pragma unroll
        for (int mi = 0; mi < 2; ++mi)
            #pragma unroll
            for (int jj = 0; jj < 4; ++jj)
                xout[(size_t)(crow + mi * 16 + jj) * HH + ccol] =
                    (bf16_t)(acc[mi][j][jj] + bv);
    }
}

// ---------------- single fused step kernel: gather + 3 GEMMs + gates + Hf-next ----------------
// 256 blocks x 256 thr (4 waves), 16 rows/block, LDS 64.5 KB -> 2 blocks/CU.
// XCD partition: bids with (bid%8)<4 -> encoder 0, else encoder 1 (L2 locality only).
__global__ __launch_bounds__(256) void k_step(
    const bf16_t* __restrict__ xbf,
    const int* __restrict__ idx1, const int* __restrict__ idx2, const int l,
    const bf16_t* __restrict__ UfWt, const float* __restrict__ Ufb,
    const bf16_t* __restrict__ UiWt, const float* __restrict__ Uib,
    const bf16_t* __restrict__ WWt, const float* __restrict__ Wb,
    const bf16_t* __restrict__ hprev, const float* __restrict__ cprev,
    const bf16_t* __restrict__ HfPrev,
    bf16_t* __restrict__ hnext, float* __restrict__ cnext,
    bf16_t* __restrict__ HfNext)
{
    __shared__ __align__(16) bf16_t sh[16 * 256];     // hsum, then h_next (both swizzled)
    __shared__ __align__(16) bf16_t WxL[16 * 1024];   // 32 KB
    __shared__ __align__(16) bf16_t iuoL[16 * 768];   // 24 KB
    __shared__ int childL[16][KK];

    const int t = threadIdx.x;
    const int bid = blockIdx.x;
    const int e = (bid >> 2) & 1;                      // XCD 0-3 -> enc0, 4-7 -> enc1
    const int rIdx = (bid >> 3) * 4 + (bid & 3);       // 0..127 within encoder
    const int n0 = rIdx * 16;
    const int g0 = e * NN + n0;
    const int lane = t & 63, w = t >> 6;
    const int r = lane & 15, kg = lane >> 4;
    const f32x4 zero = {0.f, 0.f, 0.f, 0.f};

    // ---- phase 0: x-row prefetch (regs) + child ids ----
    const bf16_t* xrow = xbf + ((size_t)e * LN + (size_t)l * NN + n0 + r) * HH + kg * 8;
    bf16x8 aWx[8];
    #pragma unroll
    for (int k = 0; k < 8; ++k) aWx[k] = *(const bf16x8*)(xrow + k * 32);
    if (t < 128) {
        const int rr = t >> 3, k = t & 7;
        const int il = ((e ? idx2 : idx1) + ((size_t)l * NN + n0) * KK)[rr * KK + k];
        childL[rr][k] = (il >= 1) ? (e * NN + il - 1) : -1;
    }
    __syncthreads();

    // ---- phase 1: hsum gather (16 rows x 32 slices; 2 slices/thread) ----
    {
        const int rr = t >> 4, s0 = t & 15;
        #pragma unroll
        for (int h16 = 0; h16 < 2; ++h16) {
            const int s = s0 + 16 * h16;
            float acc[8] = {0.f, 0.f, 0.f, 0.f, 0.f, 0.f, 0.f, 0.f};
            #pragma unroll
            for (int k = 0; k < KK; ++k) {
                const int ch = childL[rr][k];
                if (ch >= 0) {
                    const bf16x8 v = *(const bf16x8*)(hprev + (size_t)ch * HH + s * 8);
                    #pragma unroll
                    for (int jj = 0; jj < 8; ++jj) acc[jj] += (float)v[jj];
                }
            }
            bf16x8 o;
            #pragma unroll
            for (int jj = 0; jj < 8; ++jj) o[jj] = (bf16_t)acc[jj];
            const int ss = (s + 4 * (rr & 7)) & 31;
            *(bf16x8*)(sh + rr * 256 + ss * 8) = o;
        }
    }
    __syncthreads();

    // ---- phase 2a: Wx = x_l @ WW + Wb (wave w -> 16 col-tiles) ----
    {
        f32x4 acc[16];
        #pragma unroll
        for (int j = 0; j < 16; ++j) acc[j] = zero;
        for (int k0 = 0; k0 < 8; ++k0) {
            #pragma unroll
            for (int j = 0; j < 16; ++j) {
                const bf16x8 b = *(const bf16x8*)(WWt + (size_t)((w * 16 + j) * 16 + r) * HH + k0 * 32 + kg * 8);
                acc[j] = __builtin_amdgcn_mfma_f32_16x16x32_bf16(aWx[k0], b, acc[j], 0, 0, 0);
            }
        }
        #pragma unroll
        for (int j = 0; j < 16; ++j) {
            const int col = (w * 16 + j) * 16 + r;
            const float bv = Wb[col];
            #pragma unroll
            for (int jj = 0; jj < 4; ++jj)
                WxL[(size_t)(kg * 4 + jj) * 1024 + col] = (bf16_t)(acc[j][jj] + bv);
        }
    }
    // ---- phase 2b: iuo = hsum @ UiW + Uib (wave w -> 12 col-tiles) ----
    {
        f32x4 acc[12];
        #pragma unroll
        for (int j = 0; j < 12; ++j) acc[j] = zero;
        for (int k0 = 0; k0 < 8; ++k0) {
            const int ss = (k0 * 4 + kg + 4 * (r & 7)) & 31;
            const bf16x8 a = *(const bf16x8*)(sh + r * 256 + ss * 8);
            #pragma unroll
            for (int j = 0; j < 12; ++j) {
                const bf16x8 b = *(const bf16x8*)(UiWt + (size_t)((w * 12 + j) * 16 + r) * HH + k0 * 32 + kg * 8);
                acc[j] = __builtin_amdgcn_mfma_f32_16x16x32_bf16(a, b, acc[j], 0, 0, 0);
            }
        }
        #pragma unroll
        for (int j = 0; j < 12; ++j) {
            const int col = (w * 12 + j) * 16 + r;
            const float bv = Uib[col];
            #pragma unroll
            for (int jj = 0; jj < 4; ++jj)
                iuoL[(size_t)(kg * 4 + jj) * 768 + col] = (bf16_t)(acc[j][jj] + bv);
        }
    }
    __syncthreads();

    // ---- phase 3: gates (col = t; gather HfPrev/cprev children; write h,c; h_next -> sh) ----
    {
        const int col = t;
        #pragma unroll
        for (int rr = 0; rr < 16; ++rr) {
            const int g = g0 + rr;
            const float Wf = (float)WxL[(size_t)rr * 1024 + col];
            const float Wi = (float)WxL[(size_t)rr * 1024 + 256 + col];
            const float Wu = (float)WxL[(size_t)rr * 1024 + 512 + col];
            const float Wo = (float)WxL[(size_t)rr * 1024 + 768 + col];
            float bfa = 0.f;
            #pragma unroll
            for (int k = 0; k < KK; ++k) {
                const int ch = childL[rr][k];
                if (ch >= 0) {
                    const float hf = (float)HfPrev[(size_t)ch * HH + col];
                    const float fk = sigmoidf_(Wf + hf);
                    bfa = fmaf(fk, cprev[(size_t)ch * HH + col], bfa);
                }
            }
            const float ig = sigmoidf_((float)iuoL[(size_t)rr * 768 + col] + Wi);
            const float ug = tanhf((float)iuoL[(size_t)rr * 768 + 256 + col] + Wu);
            const float og = sigmoidf_((float)iuoL[(size_t)rr * 768 + 512 + col] + Wo);
            const float nc = fmaf(ig, ug, bfa);
            const float nh = og * tanhf(nc);
            cnext[(size_t)g * HH + col] = nc;
            const bf16_t nhb = (bf16_t)nh;
            hnext[(size_t)g * HH + col] = nhb;
            const int ss = ((col >> 3) + 4 * (rr & 7)) & 31;
            sh[rr * 256 + ss * 8 + (col & 7)] = nhb;
        }
    }

    if (l < LL - 1) {
        __syncthreads();
        // ---- phase 4: Hf_next = h_next @ UfW + Ufb (wave w -> 4 col-tiles) ----
        f32x4 acc[4];
        #pragma unroll
        for (int j = 0; j < 4; ++j) acc[j] = zero;
        for (int k0 = 0; k0 < 8; ++k0) {
            const int ss = (k0 * 4 + kg + 4 * (r & 7)) & 31;
            const bf16x8 a = *(const bf16x8*)(sh + r * 256 + ss * 8);
            #pragma unroll
            for (int j = 0; j < 4; ++j) {
                const bf16x8 b = *(const bf16x8*)(UfWt + (size_t)((w * 4 + j) * 16 + r) * HH + k0 * 32 + kg * 8);
                acc[j] = __builtin_amdgcn_mfma_f32_16x16x32_bf16(a, b, acc[j], 0, 0, 0);
            }
        }
        #pragma unroll
        for (int j = 0; j < 4; ++j) {
            const int col = (w * 4 + j) * 16 + r;
            const float bv = Ufb[col];
            #pragma unroll
            for (int jj = 0; jj < 4; ++jj)
                HfNext[(size_t)(g0 + kg * 4 + jj) * HH + col] = (bf16_t)(acc[j][jj] + bv);
        }
    }
}

// ---------------- siamese head ----------------
__global__ __launch_bounds__(256) void k_final(
    const bf16_t* __restrict__ hlast, const bf16_t* __restrict__ xbf,
    const float* __restrict__ dW, const float* __restrict__ db,
    const float* __restrict__ oW, const float* __restrict__ ob,
    float* __restrict__ out)
{
    __shared__ __align__(16) float ad[8][HH];
    __shared__ __align__(16) float xx[8][512];
    const int t = threadIdx.x;
    const int n0 = blockIdx.x * 8;
    const size_t xoff1 = (size_t)(LL - 1) * NN * HH;
    const size_t xoff2 = (size_t)LN * HH + xoff1;
    #pragma unroll
    for (int rr = 0; rr < 8; ++rr) {
        const int n = n0 + rr;
        const float h1 = (float)hlast[(size_t)n * HH + t] + (float)xbf[xoff1 + (size_t)n * HH + t];
        const float h2 = (float)hlast[((size_t)NN + n) * HH + t] + (float)xbf[xoff2 + (size_t)n * HH + t];
        ad[rr][t] = fabsf(h1 - h2);
    }
    __syncthreads();
    float a0[8], a1[8];
    #pragma unroll
    for (int rr = 0; rr < 8; ++rr) { a0[rr] = 0.f; a1[rr] = 0.f; }
    for (int k = 0; k < HH; k += 4) {
        #pragma unroll
        for (int kk = 0; kk < 4; ++kk) {
            const float b0 = dW[(size_t)(k + kk) * 512 + t];
            const float b1 = dW[(size_t)(k + kk) * 512 + 256 + t];
            #pragma unroll
            for (int rr = 0; rr < 8; ++rr) {
                const float av = ad[rr][k + kk];
                a0[rr] = fmaf(av, b0, a0[rr]);
                a1[rr] = fmaf(av, b1, a1[rr]);
            }
        }
    }
    const float db0 = db[t], db1 = db[256 + t];
    #pragma unroll
    for (int rr = 0; rr < 8; ++rr) {
        xx[rr][t] = tanhf(a0[rr] + db0);
        xx[rr][256 + t] = tanhf(a1[rr] + db1);
    }
    __syncthreads();
    const int w = t >> 6, lane = t & 63;
    for (int rr = w; rr < 8; rr += 4) {
        float p0 = 0.f, p1 = 0.f;
        for (int k = lane; k < 512; k += 64) {
            const float xv = xx[rr][k];
            p0 = fmaf(xv, oW[2 * k + 0], p0);
            p1 = fmaf(xv, oW[2 * k + 1], p1);
        }
        #pragma unroll
        for (int off = 32; off > 0; off >>= 1) {
            p0 += __shfl_down(p0, off);
            p1 += __shfl_down(p1, off);
        }
        if (lane == 0) {
            const float l0 = p0 + ob[0], l1 = p1 + ob[1];
            const float mx = fmaxf(l0, l1);
            const float e0 = expf(l0 - mx), e1 = expf(l1 - mx);
            const float inv = 1.f / (e0 + e1);
            out[(size_t)(n0 + rr) * 2 + 0] = e0 * inv;
            out[(size_t)(n0 + rr) * 2 + 1] = e1 * inv;
        }
    }
}

extern "C" void kernel_launch(void* const* d_in, const int* in_sizes, int n_in,
                              void* d_out, int out_size, void* d_ws, size_t ws_size,
                              hipStream_t stream) {
    (void)in_sizes; (void)n_in; (void)out_size; (void)ws_size;
    const int*   tok1 = (const int*)d_in[0];
    const int*   idx1 = (const int*)d_in[1];
    const int*   tok2 = (const int*)d_in[2];
    const int*   idx2 = (const int*)d_in[3];
    const float* E    = (const float*)d_in[4];
    const float* linW = (const float*)d_in[5];
    const float* linb = (const float*)d_in[6];
    const float* UfW  = (const float*)d_in[7];
    const float* Ufb  = (const float*)d_in[8];
    const float* UiW  = (const float*)d_in[9];
    const float* Uib  = (const float*)d_in[10];
    const float* WW   = (const float*)d_in[11];
    const float* Wb   = (const float*)d_in[12];
    const float* dW   = (const float*)d_in[13];
    const float* db   = (const float*)d_in[14];
    const float* oW   = (const float*)d_in[15];
    const float* ob   = (const float*)d_in[16];
    float* out = (float*)d_out;

    // ws: xbf | UNION{ Ebf (dead after embed) | hA hB HfA HfB cA cB } | weights  (~52.3 MB)
    bf16_t* xbf = (bf16_t*)d_ws;                        // 12,582,912 elems
    char*   uni = (char*)(xbf + (size_t)12582912);
    bf16_t* Ebf = (bf16_t*)uni;                         // 12,800,000 elems (25.6 MB)
    bf16_t* hA  = (bf16_t*)uni;
    bf16_t* hB  = hA  + (size_t)1048576;
    bf16_t* HfA = hB  + (size_t)1048576;
    bf16_t* HfB = HfA + (size_t)1048576;
    float*  cA  = (float*)(HfB + (size_t)1048576);
    float*  cB  = cA + (size_t)1048576;                 // step bufs 16 MB < 25.6 MB
    bf16_t* linWt = (bf16_t*)(uni + 25600000);          // 262,144
    bf16_t* WWt   = linWt + (size_t)262144;             // 262,144
    bf16_t* UfWt  = WWt   + (size_t)262144;             // 65,536
    bf16_t* UiWt  = UfWt  + (size_t)65536;              // 196,608

    k_cvtE<<<2048, 256, 0, stream>>>(E, Ebf, VV * HH / 4);
    k_cvtW<<<3072, 256, 0, stream>>>(linW, WW, UfW, UiW, linWt, WWt, UfWt, UiWt);

    k_embed<<<768, 256, 0, stream>>>(tok1, tok2, Ebf, linWt, linb, xbf);

    bf16_t *hp = hA, *hn = hB, *fp = HfA, *fn = HfB;
    float  *cp = cA, *cn = cB;
    for (int l = 0; l < LL; ++l) {
        // l==0: idx[0] all -1 -> hprev/cprev/HfPrev never read (poison/alias safe)
        k_step<<<256, 256, 0, stream>>>(xbf, idx1, idx2, l,
                                        UfWt, Ufb, UiWt, Uib, WWt, Wb,
                                        hp, cp, fp, hn, cn, fn);
        bf16_t* th = hp; hp = hn; hn = th;
        float*  tc = cp; cp = cn; cn = tc;
        bf16_t* tf = fp; fp = fn; fn = tf;
    }

    k_final<<<NN / 8, 256, 0, stream>>>(hp, xbf, dW, db, oW, ob, out);
}

// Round 8
// 886.878 us; speedup vs baseline: 1.8032x; 1.4908x over previous
//
#include <hip/hip_runtime.h>

#define LL 12
#define NN 2048
#define KK 8
#define SS 4
#define HH 256
#define LN (LL*NN)
#define VV 50000

typedef __bf16 bf16_t;
typedef __bf16 bf16x8 __attribute__((ext_vector_type(8)));
typedef __bf16 bf16x4v __attribute__((ext_vector_type(4)));
typedef float f32x4 __attribute__((ext_vector_type(4)));

__device__ __forceinline__ float sigmoidf_(float x) { return 1.f / (1.f + expf(-x)); }

// ---------------- E f32 -> bf16 ----------------
__global__ __launch_bounds__(256) void k_cvtE(const float* __restrict__ src,
                                              bf16_t* __restrict__ dst, int n4)
{
    int i = blockIdx.x * 256 + threadIdx.x;
    const int stride = gridDim.x * 256;
    for (; i < n4; i += stride) {
        const float4 v = ((const float4*)src)[i];
        bf16x4v o;
        o[0] = (bf16_t)v.x; o[1] = (bf16_t)v.y; o[2] = (bf16_t)v.z; o[3] = (bf16_t)v.w;
        ((bf16x4v*)dst)[i] = o;
    }
}

// ---------------- weight transposes (f32 (K,N) -> bf16 (N,K)) ----------------
__global__ __launch_bounds__(256) void k_cvtW(
    const float* __restrict__ linW, const float* __restrict__ WW,
    const float* __restrict__ UfW, const float* __restrict__ UiW,
    bf16_t* __restrict__ linWt, bf16_t* __restrict__ WWt,
    bf16_t* __restrict__ UfWt, bf16_t* __restrict__ UiWt)
{
    int i = blockIdx.x * 256 + threadIdx.x;      // total 786432
    if (i < 262144) {                            // linW (1024,256) -> (256,1024)
        const int rr = i >> 8, cc = i & 255;
        linWt[(size_t)cc * 1024 + rr] = (bf16_t)linW[i];
        return;
    }
    i -= 262144;
    if (i < 262144) {                            // WW (256,1024) -> (1024,256)
        const int rr = i >> 10, cc = i & 1023;
        WWt[(size_t)cc * 256 + rr] = (bf16_t)WW[i];
        return;
    }
    i -= 262144;
    if (i < 65536) {                             // UfW (256,256) -> (256,256)
        const int rr = i >> 8, cc = i & 255;
        UfWt[(size_t)cc * 256 + rr] = (bf16_t)UfW[i];
        return;
    }
    i -= 65536;
    if (i < 196608) {                            // UiW (256,768) -> (768,256)
        const int rr = i / 768, cc = i - rr * 768;
        UiWt[(size_t)cc * 256 + rr] = (bf16_t)UiW[i];
    }
}

// ---------------- embed GEMM (measured-best): 768 blocks x 256 thr ----------------
__global__ __launch_bounds__(256) void k_embed(
    const int* __restrict__ tok1, const int* __restrict__ tok2,
    const bf16_t* __restrict__ Ebf, const bf16_t* __restrict__ linWt,
    const float* __restrict__ linb, bf16_t* __restrict__ xout)
{
    __shared__ int toff[64][SS];
    const int t = threadIdx.x;
    const int m0 = blockIdx.x * 64;
    {
        const int lr = t >> 2, s = t & 3;
        const int m = m0 + lr;
        const int e = (m >= LN) ? 1 : 0;
        const int rrow = m - e * LN;
        const int* tok = e ? tok2 : tok1;
        toff[lr][s] = tok[(size_t)rrow * SS + s] * HH;
    }
    __syncthreads();
    const int lane = t & 63, w = t >> 6;
    const int wm = w >> 1, wn = w & 1;
    const int r = lane & 15, kg = lane >> 4;
    const int lr0 = wm * 32 + r, lr1 = lr0 + 16;
    const bf16_t* bp[8];
    #pragma unroll
    for (int j = 0; j < 8; ++j)
        bp[j] = linWt + (size_t)(wn * 128 + j * 16 + r) * 1024 + kg * 8;

    const f32x4 zero = {0.f, 0.f, 0.f, 0.f};
    f32x4 acc[2][8];
    #pragma unroll
    for (int mi = 0; mi < 2; ++mi)
        #pragma unroll
        for (int j = 0; j < 8; ++j) acc[mi][j] = zero;

    for (int k0 = 0; k0 < 1024; k0 += 32) {
        const int s = k0 >> 8, off = (k0 & 255) + kg * 8;
        const bf16x8 a0 = *(const bf16x8*)(Ebf + (size_t)toff[lr0][s] + off);
        const bf16x8 a1 = *(const bf16x8*)(Ebf + (size_t)toff[lr1][s] + off);
        #pragma unroll
        for (int j = 0; j < 8; ++j) {
            const bf16x8 b = *(const bf16x8*)bp[j];
            acc[0][j] = __builtin_amdgcn_mfma_f32_16x16x32_bf16(a0, b, acc[0][j], 0, 0, 0);
            acc[1][j] = __builtin_amdgcn_mfma_f32_16x16x32_bf16(a1, b, acc[1][j], 0, 0, 0);
            bp[j] += 32;
        }
    }
    const int crow = m0 + wm * 32 + kg * 4;
    #pragma unroll
    for (int j = 0; j < 8; ++j) {
        const int ccol = wn * 128 + j * 16 + r;
        const float bv = linb[ccol];
        #pragma unroll
        for (int mi = 0; mi < 2; ++mi)
            #pragma unroll
            for (int jj = 0; jj < 4; ++jj)
                xout[(size_t)(crow + mi * 16 + jj) * HH + ccol] =
                    (bf16_t)(acc[mi][j][jj] + bv);
    }
}

// ---------------- fused step kernel: 256 blocks x 512 thr (8 waves), 16 rows/block ----------------
// gather + Wx/iuo GEMMs + gates + Hf-next; h/c/Hf ping-pong across launches.
__global__ __launch_bounds__(512) void k_step(
    const bf16_t* __restrict__ xbf,
    const int* __restrict__ idx1, const int* __restrict__ idx2, const int l,
    const bf16_t* __restrict__ UfWt, const float* __restrict__ Ufb,
    const bf16_t* __restrict__ UiWt, const float* __restrict__ Uib,
    const bf16_t* __restrict__ WWt, const float* __restrict__ Wb,
    const bf16_t* __restrict__ hprev, const float* __restrict__ cprev,
    const bf16_t* __restrict__ HfPrev,
    bf16_t* __restrict__ hnext, float* __restrict__ cnext,
    bf16_t* __restrict__ HfNext)
{
    __shared__ __align__(16) bf16_t sh[16 * 256];     // hsum, then h_next (both swizzled)
    __shared__ __align__(16) bf16_t WxL[16 * 1024];   // 32 KB
    __shared__ __align__(16) bf16_t iuoL[16 * 768];   // 24 KB
    __shared__ int childL[16][KK];

    const int t = threadIdx.x;
    const int bid = blockIdx.x;
    const int e  = bid >> 7;
    const int n0 = (bid & 127) * 16;
    const int g0 = e * NN + n0;
    const int lane = t & 63, w = t >> 6;
    const int r = lane & 15, kg = lane >> 4;
    const f32x4 zero = {0.f, 0.f, 0.f, 0.f};

    // ---- phase 0: child ids + x-row prefetch into registers ----
    if (t < 128) {
        const int rr = t >> 3, k = t & 7;
        const int il = ((e ? idx2 : idx1) + ((size_t)l * NN + n0) * KK)[rr * KK + k];
        childL[rr][k] = (il >= 1) ? (e * NN + il - 1) : -1;
    }
    const bf16_t* xrow = xbf + ((size_t)e * LN + (size_t)l * NN + n0 + r) * HH + kg * 8;
    bf16x8 aWx[8];
    #pragma unroll
    for (int k = 0; k < 8; ++k) aWx[k] = *(const bf16x8*)(xrow + k * 32);
    __syncthreads();

    // ---- phase 1: hsum gather (16 rows x 32 slices of 16B; one slice/thread) ----
    {
        const int rr = t >> 5, c8 = t & 31;
        float acc[8] = {0.f, 0.f, 0.f, 0.f, 0.f, 0.f, 0.f, 0.f};
        #pragma unroll
        for (int k = 0; k < KK; ++k) {
            const int ch = childL[rr][k];
            if (ch >= 0) {
                const bf16x8 v = *(const bf16x8*)(hprev + (size_t)ch * HH + c8 * 8);
                #pragma unroll
                for (int jj = 0; jj < 8; ++jj) acc[jj] += (float)v[jj];
            }
        }
        bf16x8 o;
        #pragma unroll
        for (int jj = 0; jj < 8; ++jj) o[jj] = (bf16_t)acc[jj];
        const int ss = (c8 + 4 * (rr & 7)) & 31;
        *(bf16x8*)(sh + rr * 256 + ss * 8) = o;
    }
    __syncthreads();

    // ---- phase 2a: Wx = x_l @ WW + Wb  (wave w -> col tiles 8w..8w+7) ----
    {
        const bf16_t* bw[8];
        #pragma unroll
        for (int j = 0; j < 8; ++j)
            bw[j] = WWt + (size_t)((8 * w + j) * 16 + r) * HH + kg * 8;
        f32x4 acc[8];
        #pragma unroll
        for (int j = 0; j < 8; ++j) acc[j] = zero;
        #pragma unroll
        for (int k = 0; k < 8; ++k) {
            #pragma unroll
            for (int j = 0; j < 8; ++j) {
                const bf16x8 b = *(const bf16x8*)bw[j];
                acc[j] = __builtin_amdgcn_mfma_f32_16x16x32_bf16(aWx[k], b, acc[j], 0, 0, 0);
                bw[j] += 32;
            }
        }
        #pragma unroll
        for (int j = 0; j < 8; ++j) {
            const int col = (8 * w + j) * 16 + r;
            const float bv = Wb[col];
            #pragma unroll
            for (int jj = 0; jj < 4; ++jj)
                WxL[(size_t)(kg * 4 + jj) * 1024 + col] = (bf16_t)(acc[j][jj] + bv);
        }
    }
    // ---- phase 2b: iuo = hsum @ UiW + Uib  (wave w -> col tiles 6w..6w+5) ----
    {
        const bf16_t* bu[6];
        #pragma unroll
        for (int j = 0; j < 6; ++j)
            bu[j] = UiWt + (size_t)((6 * w + j) * 16 + r) * HH + kg * 8;
        f32x4 acc[6];
        #pragma unroll
        for (int j = 0; j < 6; ++j) acc[j] = zero;
        for (int k0 = 0; k0 < HH; k0 += 32) {
            const int ss = (((k0 >> 3) + kg) + 4 * (r & 7)) & 31;
            const bf16x8 a = *(const bf16x8*)(sh + r * 256 + ss * 8);
            #pragma unroll
            for (int j = 0; j < 6; ++j) {
                const bf16x8 b = *(const bf16x8*)bu[j];
                acc[j] = __builtin_amdgcn_mfma_f32_16x16x32_bf16(a, b, acc[j], 0, 0, 0);
                bu[j] += 32;
            }
        }
        #pragma unroll
        for (int j = 0; j < 6; ++j) {
            const int col = (6 * w + j) * 16 + r;
            const float bv = Uib[col];
            #pragma unroll
            for (int jj = 0; jj < 4; ++jj)
                iuoL[(size_t)(kg * 4 + jj) * 768 + col] = (bf16_t)(acc[j][jj] + bv);
        }
    }
    __syncthreads();

    // ---- phase 3: gates (col = t&255; 8 rows/thread; plain row loop) ----
    {
        const int col = t & 255, rb2 = t >> 8;
        for (int i = 0; i < 8; ++i) {
            const int rr = i * 2 + rb2;
            const int g = g0 + rr;
            const float Wf = (float)WxL[(size_t)rr * 1024 + col];
            const float Wi = (float)WxL[(size_t)rr * 1024 + 256 + col];
            const float Wu = (float)WxL[(size_t)rr * 1024 + 512 + col];
            const float Wo = (float)WxL[(size_t)rr * 1024 + 768 + col];
            float bfa = 0.f;
            #pragma unroll
            for (int k = 0; k < KK; ++k) {
                const int ch = childL[rr][k];
                if (ch >= 0) {
                    const float hf = (float)HfPrev[(size_t)ch * HH + col];
                    const float fk = sigmoidf_(Wf + hf);
                    bfa = fmaf(fk, cprev[(size_t)ch * HH + col], bfa);
                }
            }
            const float ig = sigmoidf_((float)iuoL[(size_t)rr * 768 + col] + Wi);
            const float ug = tanhf((float)iuoL[(size_t)rr * 768 + 256 + col] + Wu);
            const float og = sigmoidf_((float)iuoL[(size_t)rr * 768 + 512 + col] + Wo);
            const float nc = fmaf(ig, ug, bfa);
            const float nh = og * tanhf(nc);
            cnext[(size_t)g * HH + col] = nc;
            const bf16_t nhb = (bf16_t)nh;
            hnext[(size_t)g * HH + col] = nhb;
            const int ss = ((col >> 3) + 4 * (rr & 7)) & 31;
            sh[rr * 256 + ss * 8 + (col & 7)] = nhb;
        }
    }

    if (l < LL - 1) {
        __syncthreads();
        // ---- phase 4: Hf_next = h_next @ UfW + Ufb (wave w -> tiles 2w, 2w+1) ----
        const int ct0 = 2 * w;
        const bf16_t* bq0 = UfWt + (size_t)(ct0 * 16 + r) * HH + kg * 8;
        const bf16_t* bq1 = bq0 + (size_t)16 * HH;
        f32x4 ac0 = zero, ac1 = zero;
        for (int k0 = 0; k0 < HH; k0 += 32) {
            const int ss = (((k0 >> 3) + kg) + 4 * (r & 7)) & 31;
            const bf16x8 a = *(const bf16x8*)(sh + r * 256 + ss * 8);
            const bf16x8 b0 = *(const bf16x8*)bq0;
            const bf16x8 b1 = *(const bf16x8*)bq1;
            ac0 = __builtin_amdgcn_mfma_f32_16x16x32_bf16(a, b0, ac0, 0, 0, 0);
            ac1 = __builtin_amdgcn_mfma_f32_16x16x32_bf16(a, b1, ac1, 0, 0, 0);
            bq0 += 32; bq1 += 32;
        }
        const int c0 = ct0 * 16 + r, c1 = c0 + 16;
        const float bv0 = Ufb[c0], bv1 = Ufb[c1];
        #pragma unroll
        for (int jj = 0; jj < 4; ++jj) {
            HfNext[(size_t)(g0 + kg * 4 + jj) * HH + c0] = (bf16_t)(ac0[jj] + bv0);
            HfNext[(size_t)(g0 + kg * 4 + jj) * HH + c1] = (bf16_t)(ac1[jj] + bv1);
        }
    }
}

// ---------------- siamese head ----------------
__global__ __launch_bounds__(256) void k_final(
    const bf16_t* __restrict__ hlast, const bf16_t* __restrict__ xbf,
    const float* __restrict__ dW, const float* __restrict__ db,
    const float* __restrict__ oW, const float* __restrict__ ob,
    float* __restrict__ out)
{
    __shared__ __align__(16) float ad[8][HH];
    __shared__ __align__(16) float xx[8][512];
    const int t = threadIdx.x;
    const int n0 = blockIdx.x * 8;
    const size_t xoff1 = (size_t)(LL - 1) * NN * HH;
    const size_t xoff2 = (size_t)LN * HH + xoff1;
    #pragma unroll
    for (int rr = 0; rr < 8; ++rr) {
        const int n = n0 + rr;
        const float h1 = (float)hlast[(size_t)n * HH + t] + (float)xbf[xoff1 + (size_t)n * HH + t];
        const float h2 = (float)hlast[((size_t)NN + n) * HH + t] + (float)xbf[xoff2 + (size_t)n * HH + t];
        ad[rr][t] = fabsf(h1 - h2);
    }
    __syncthreads();
    float a0[8], a1[8];
    #pragma unroll
    for (int rr = 0; rr < 8; ++rr) { a0[rr] = 0.f; a1[rr] = 0.f; }
    for (int k = 0; k < HH; k += 4) {
        #pragma unroll
        for (int kk = 0; kk < 4; ++kk) {
            const float b0 = dW[(size_t)(k + kk) * 512 + t];
            const float b1 = dW[(size_t)(k + kk) * 512 + 256 + t];
            #pragma unroll
            for (int rr = 0; rr < 8; ++rr) {
                const float av = ad[rr][k + kk];
                a0[rr] = fmaf(av, b0, a0[rr]);
                a1[rr] = fmaf(av, b1, a1[rr]);
            }
        }
    }
    const float db0 = db[t], db1 = db[256 + t];
    #pragma unroll
    for (int rr = 0; rr < 8; ++rr) {
        xx[rr][t] = tanhf(a0[rr] + db0);
        xx[rr][256 + t] = tanhf(a1[rr] + db1);
    }
    __syncthreads();
    const int w = t >> 6, lane = t & 63;
    for (int rr = w; rr < 8; rr += 4) {
        float p0 = 0.f, p1 = 0.f;
        for (int k = lane; k < 512; k += 64) {
            const float xv = xx[rr][k];
            p0 = fmaf(xv, oW[2 * k + 0], p0);
            p1 = fmaf(xv, oW[2 * k + 1], p1);
        }
        #pragma unroll
        for (int off = 32; off > 0; off >>= 1) {
            p0 += __shfl_down(p0, off);
            p1 += __shfl_down(p1, off);
        }
        if (lane == 0) {
            const float l0 = p0 + ob[0], l1 = p1 + ob[1];
            const float mx = fmaxf(l0, l1);
            const float e0 = expf(l0 - mx), e1 = expf(l1 - mx);
            const float inv = 1.f / (e0 + e1);
            out[(size_t)(n0 + rr) * 2 + 0] = e0 * inv;
            out[(size_t)(n0 + rr) * 2 + 1] = e1 * inv;
        }
    }
}

extern "C" void kernel_launch(void* const* d_in, const int* in_sizes, int n_in,
                              void* d_out, int out_size, void* d_ws, size_t ws_size,
                              hipStream_t stream) {
    (void)in_sizes; (void)n_in; (void)out_size; (void)ws_size;
    const int*   tok1 = (const int*)d_in[0];
    const int*   idx1 = (const int*)d_in[1];
    const int*   tok2 = (const int*)d_in[2];
    const int*   idx2 = (const int*)d_in[3];
    const float* E    = (const float*)d_in[4];
    const float* linW = (const float*)d_in[5];
    const float* linb = (const float*)d_in[6];
    const float* UfW  = (const float*)d_in[7];
    const float* Ufb  = (const float*)d_in[8];
    const float* UiW  = (const float*)d_in[9];
    const float* Uib  = (const float*)d_in[10];
    const float* WW   = (const float*)d_in[11];
    const float* Wb   = (const float*)d_in[12];
    const float* dW   = (const float*)d_in[13];
    const float* db   = (const float*)d_in[14];
    const float* oW   = (const float*)d_in[15];
    const float* ob   = (const float*)d_in[16];
    float* out = (float*)d_out;

    // ws: xbf | UNION{ Ebf (dead after embed) | hA hB HfA HfB cA cB } | weights  (~52.3 MB)
    bf16_t* xbf = (bf16_t*)d_ws;                        // 12,582,912 elems
    char*   uni = (char*)(xbf + (size_t)12582912);
    bf16_t* Ebf = (bf16_t*)uni;                         // 12,800,000 elems (25.6 MB)
    bf16_t* hA  = (bf16_t*)uni;
    bf16_t* hB  = hA  + (size_t)1048576;
    bf16_t* HfA = hB  + (size_t)1048576;
    bf16_t* HfB = HfA + (size_t)1048576;
    float*  cA  = (float*)(HfB + (size_t)1048576);
    float*  cB  = cA + (size_t)1048576;                 // step bufs 16 MB < 25.6 MB
    bf16_t* linWt = (bf16_t*)(uni + 25600000);          // 262,144
    bf16_t* WWt   = linWt + (size_t)262144;             // 262,144
    bf16_t* UfWt  = WWt   + (size_t)262144;             // 65,536
    bf16_t* UiWt  = UfWt  + (size_t)65536;              // 196,608

    k_cvtE<<<2048, 256, 0, stream>>>(E, Ebf, VV * HH / 4);
    k_cvtW<<<3072, 256, 0, stream>>>(linW, WW, UfW, UiW, linWt, WWt, UfWt, UiWt);

    k_embed<<<768, 256, 0, stream>>>(tok1, tok2, Ebf, linWt, linb, xbf);

    bf16_t *hp = hA, *hn = hB, *fp = HfA, *fn = HfB;
    float  *cp = cA, *cn = cB;
    for (int l = 0; l < LL; ++l) {
        // l==0: idx[0] all -1 -> hprev/cprev/HfPrev never read (poison/alias safe)
        k_step<<<256, 512, 0, stream>>>(xbf, idx1, idx2, l,
                                        UfWt, Ufb, UiWt, Uib, WWt, Wb,
                                        hp, cp, fp, hn, cn, fn);
        bf16_t* th = hp; hp = hn; hn = th;
        float*  tc = cp; cp = cn; cn = tc;
        bf16_t* tf = fp; fp = fn; fn = tf;
    }

    k_final<<<NN / 8, 256, 0, stream>>>(hp, xbf, dW, db, oW, ob, out);
}

// Round 9
// 711.472 us; speedup vs baseline: 2.2477x; 1.2465x over previous
//
#include <hip/hip_runtime.h>

#define LL 12
#define NN 2048
#define KK 8
#define SS 4
#define HH 256
#define LN (LL*NN)
#define VV 50000
#define ZROW 4096
#define SROW 2048   // bytes per packed state row: [c f32 256 | h bf16 256 | Hf bf16 256]

typedef __bf16 bf16_t;
typedef __bf16 bf16x8 __attribute__((ext_vector_type(8)));
typedef __bf16 bf16x4v __attribute__((ext_vector_type(4)));
typedef float f32x4 __attribute__((ext_vector_type(4)));

__device__ __forceinline__ float sigmoidf_(float x) { return 1.f / (1.f + expf(-x)); }

// ---------------- E f32 -> bf16 ----------------
__global__ __launch_bounds__(256) void k_cvtE(const float* __restrict__ src,
                                              bf16_t* __restrict__ dst, int n4)
{
    int i = blockIdx.x * 256 + threadIdx.x;
    const int stride = gridDim.x * 256;
    for (; i < n4; i += stride) {
        const float4 v = ((const float4*)src)[i];
        bf16x4v o;
        o[0] = (bf16_t)v.x; o[1] = (bf16_t)v.y; o[2] = (bf16_t)v.z; o[3] = (bf16_t)v.w;
        ((bf16x4v*)dst)[i] = o;
    }
}

// ---------------- weight transposes (f32 (K,N) -> bf16 (N,K)) ----------------
__global__ __launch_bounds__(256) void k_cvtW(
    const float* __restrict__ linW, const float* __restrict__ WW,
    const float* __restrict__ UfW, const float* __restrict__ UiW,
    bf16_t* __restrict__ linWt, bf16_t* __restrict__ WWt,
    bf16_t* __restrict__ UfWt, bf16_t* __restrict__ UiWt)
{
    int i = blockIdx.x * 256 + threadIdx.x;      // total 786432
    if (i < 262144) {                            // linW (1024,256) -> (256,1024)
        const int rr = i >> 8, cc = i & 255;
        linWt[(size_t)cc * 1024 + rr] = (bf16_t)linW[i];
        return;
    }
    i -= 262144;
    if (i < 262144) {                            // WW (256,1024) -> (1024,256)
        const int rr = i >> 10, cc = i & 1023;
        WWt[(size_t)cc * 256 + rr] = (bf16_t)WW[i];
        return;
    }
    i -= 262144;
    if (i < 65536) {                             // UfW (256,256) -> (256,256)
        const int rr = i >> 8, cc = i & 255;
        UfWt[(size_t)cc * 256 + rr] = (bf16_t)UfW[i];
        return;
    }
    i -= 65536;
    if (i < 196608) {                            // UiW (256,768) -> (768,256)
        const int rr = i / 768, cc = i - rr * 768;
        UiWt[(size_t)cc * 256 + rr] = (bf16_t)UiW[i];
    }
}

// ---------------- zero the dummy rows of both packed state buffers ----------------
__global__ __launch_bounds__(256) void k_zero(float* __restrict__ SA, float* __restrict__ SB)
{
    const int t = threadIdx.x;
    float* a = SA + (size_t)ZROW * 512;   // 512 f32 per 2KB row
    float* b = SB + (size_t)ZROW * 512;
    a[t] = 0.f; a[t + 256] = 0.f;
    b[t] = 0.f; b[t + 256] = 0.f;
}

// ---------------- embed GEMM (measured-best): 768 blocks x 256 thr ----------------
__global__ __launch_bounds__(256) void k_embed(
    const int* __restrict__ tok1, const int* __restrict__ tok2,
    const bf16_t* __restrict__ Ebf, const bf16_t* __restrict__ linWt,
    const float* __restrict__ linb, bf16_t* __restrict__ xout)
{
    __shared__ int toff[64][SS];
    const int t = threadIdx.x;
    const int m0 = blockIdx.x * 64;
    {
        const int lr = t >> 2, s = t & 3;
        const int m = m0 + lr;
        const int e = (m >= LN) ? 1 : 0;
        const int rrow = m - e * LN;
        const int* tok = e ? tok2 : tok1;
        toff[lr][s] = tok[(size_t)rrow * SS + s] * HH;
    }
    __syncthreads();
    const int lane = t & 63, w = t >> 6;
    const int wm = w >> 1, wn = w & 1;
    const int r = lane & 15, kg = lane >> 4;
    const int lr0 = wm * 32 + r, lr1 = lr0 + 16;
    const bf16_t* bp[8];
    #pragma unroll
    for (int j = 0; j < 8; ++j)
        bp[j] = linWt + (size_t)(wn * 128 + j * 16 + r) * 1024 + kg * 8;

    const f32x4 zero = {0.f, 0.f, 0.f, 0.f};
    f32x4 acc[2][8];
    #pragma unroll
    for (int mi = 0; mi < 2; ++mi)
        #pragma unroll
        for (int j = 0; j < 8; ++j) acc[mi][j] = zero;

    for (int k0 = 0; k0 < 1024; k0 += 32) {
        const int s = k0 >> 8, off = (k0 & 255) + kg * 8;
        const bf16x8 a0 = *(const bf16x8*)(Ebf + (size_t)toff[lr0][s] + off);
        const bf16x8 a1 = *(const bf16x8*)(Ebf + (size_t)toff[lr1][s] + off);
        #pragma unroll
        for (int j = 0; j < 8; ++j) {
            const bf16x8 b = *(const bf16x8*)bp[j];
            acc[0][j] = __builtin_amdgcn_mfma_f32_16x16x32_bf16(a0, b, acc[0][j], 0, 0, 0);
            acc[1][j] = __builtin_amdgcn_mfma_f32_16x16x32_bf16(a1, b, acc[1][j], 0, 0, 0);
            bp[j] += 32;
        }
    }
    const int crow = m0 + wm * 32 + kg * 4;
    #pragma unroll
    for (int j = 0; j < 8; ++j) {
        const int ccol = wn * 128 + j * 16 + r;
        const float bv = linb[ccol];
        #pragma unroll
        for (int mi = 0; mi < 2; ++mi)
            #pragma unroll
            for (int jj = 0; jj < 4; ++jj)
                xout[(size_t)(crow + mi * 16 + jj) * HH + ccol] =
                    (bf16_t)(acc[mi][j][jj] + bv);
    }
}

// ---------------- fused step kernel: packed-state, single gather phase ----------------
// 256 blocks x 512 thr (8 waves), 16 rows/block.
__global__ __launch_bounds__(512) void k_step(
    const bf16_t* __restrict__ xbf,
    const int* __restrict__ idx1, const int* __restrict__ idx2, const int l,
    const bf16_t* __restrict__ UfWt, const float* __restrict__ Ufb,
    const bf16_t* __restrict__ UiWt, const float* __restrict__ Uib,
    const bf16_t* __restrict__ WWt, const float* __restrict__ Wb,
    const char* __restrict__ Sprev, char* __restrict__ Snext)
{
    __shared__ __align__(16) bf16_t WxL[16 * 1024];   // 32 KB
    __shared__ __align__(16) bf16_t iuoL[16 * 768];   // 24 KB
    __shared__ __align__(16) bf16_t hsumL[16 * 256];  // 8 KB (hsum, later h_next; swizzled)
    __shared__ __align__(16) float  bfaL[16 * 256];   // 16 KB
    __shared__ int childL[16][KK];

    const int t = threadIdx.x;
    const int bid = blockIdx.x;
    const int e  = bid >> 7;
    const int n0 = (bid & 127) * 16;
    const int g0 = e * NN + n0;
    const int lane = t & 63, w = t >> 6;
    const int r = lane & 15, kg = lane >> 4;
    const f32x4 zero = {0.f, 0.f, 0.f, 0.f};

    // ---- phase 0: child ids + x-row prefetch into registers ----
    if (t < 128) {
        const int rr = t >> 3, k = t & 7;
        const int il = ((e ? idx2 : idx1) + ((size_t)l * NN + n0) * KK)[rr * KK + k];
        childL[rr][k] = (il >= 1) ? (e * NN + il - 1) : ZROW;
    }
    const bf16_t* xrow = xbf + ((size_t)e * LN + (size_t)l * NN + n0 + r) * HH + kg * 8;
    bf16x8 aWx[8];
    #pragma unroll
    for (int k = 0; k < 8; ++k) aWx[k] = *(const bf16x8*)(xrow + k * 32);
    __syncthreads();

    // ---- phase 1: Wx = x_l @ WW + Wb  (wave w -> col tiles 8w..8w+7) ----
    {
        const bf16_t* bw[8];
        #pragma unroll
        for (int j = 0; j < 8; ++j)
            bw[j] = WWt + (size_t)((8 * w + j) * 16 + r) * HH + kg * 8;
        f32x4 acc[8];
        #pragma unroll
        for (int j = 0; j < 8; ++j) acc[j] = zero;
        #pragma unroll
        for (int k = 0; k < 8; ++k) {
            #pragma unroll
            for (int j = 0; j < 8; ++j) {
                const bf16x8 b = *(const bf16x8*)bw[j];
                acc[j] = __builtin_amdgcn_mfma_f32_16x16x32_bf16(aWx[k], b, acc[j], 0, 0, 0);
                bw[j] += 32;
            }
        }
        #pragma unroll
        for (int j = 0; j < 8; ++j) {
            const int col = (8 * w + j) * 16 + r;
            const float bv = Wb[col];
            #pragma unroll
            for (int jj = 0; jj < 4; ++jj)
                WxL[(size_t)(kg * 4 + jj) * 1024 + col] = (bf16_t)(acc[j][jj] + bv);
        }
    }
    __syncthreads();

    // ---- phase 2: unified gather: hsum + bfa in one pass over packed child rows ----
    {
        const int rr = t >> 5, sl = t & 31;          // 16 rows x 32 slices (8 cols each)
        const int colb = sl * 8;
        float wf[8];
        {
            const bf16x8 wv = *(const bf16x8*)(WxL + (size_t)rr * 1024 + colb);
            #pragma unroll
            for (int j = 0; j < 8; ++j) wf[j] = (float)wv[j];
        }
        float hs[8] = {0.f, 0.f, 0.f, 0.f, 0.f, 0.f, 0.f, 0.f};
        float ba[8] = {0.f, 0.f, 0.f, 0.f, 0.f, 0.f, 0.f, 0.f};
        #pragma unroll
        for (int k = 0; k < KK; ++k) {
            const char* row = Sprev + (size_t)childL[rr][k] * SROW;
            const float4 c0 = *(const float4*)(row + sl * 32);
            const float4 c1 = *(const float4*)(row + sl * 32 + 16);
            const bf16x8 hv = *(const bf16x8*)(row + 1024 + sl * 16);
            const bf16x8 fv = *(const bf16x8*)(row + 1536 + sl * 16);
            const float cc[8] = {c0.x, c0.y, c0.z, c0.w, c1.x, c1.y, c1.z, c1.w};
            #pragma unroll
            for (int j = 0; j < 8; ++j) {
                hs[j] += (float)hv[j];
                const float fk = sigmoidf_(wf[j] + (float)fv[j]);
                ba[j] = fmaf(fk, cc[j], ba[j]);
            }
        }
        bf16x8 o;
        #pragma unroll
        for (int j = 0; j < 8; ++j) o[j] = (bf16_t)hs[j];
        const int ss = (sl + 4 * (rr & 7)) & 31;
        *(bf16x8*)(hsumL + (size_t)rr * 256 + ss * 8) = o;
        f32x4 b0 = {ba[0], ba[1], ba[2], ba[3]};
        f32x4 b1 = {ba[4], ba[5], ba[6], ba[7]};
        *(f32x4*)(bfaL + (size_t)rr * 256 + colb) = b0;
        *(f32x4*)(bfaL + (size_t)rr * 256 + colb + 4) = b1;
    }
    __syncthreads();

    // ---- phase 3: iuo = hsum @ UiW + Uib  (wave w -> col tiles 6w..6w+5) ----
    {
        const bf16_t* bu[6];
        #pragma unroll
        for (int j = 0; j < 6; ++j)
            bu[j] = UiWt + (size_t)((6 * w + j) * 16 + r) * HH + kg * 8;
        f32x4 acc[6];
        #pragma unroll
        for (int j = 0; j < 6; ++j) acc[j] = zero;
        for (int k0 = 0; k0 < HH; k0 += 32) {
            const int ss = (((k0 >> 3) + kg) + 4 * (r & 7)) & 31;
            const bf16x8 a = *(const bf16x8*)(hsumL + (size_t)r * 256 + ss * 8);
            #pragma unroll
            for (int j = 0; j < 6; ++j) {
                const bf16x8 b = *(const bf16x8*)bu[j];
                acc[j] = __builtin_amdgcn_mfma_f32_16x16x32_bf16(a, b, acc[j], 0, 0, 0);
                bu[j] += 32;
            }
        }
        #pragma unroll
        for (int j = 0; j < 6; ++j) {
            const int col = (6 * w + j) * 16 + r;
            const float bv = Uib[col];
            #pragma unroll
            for (int jj = 0; jj < 4; ++jj)
                iuoL[(size_t)(kg * 4 + jj) * 768 + col] = (bf16_t)(acc[j][jj] + bv);
        }
    }
    __syncthreads();

    // ---- phase 4: gates (pure LDS; write packed c,h; h_next -> hsumL reuse) ----
    {
        const int col = t & 255, rb2 = t >> 8;
        for (int i = 0; i < 8; ++i) {
            const int rr = i * 2 + rb2;
            const int g = g0 + rr;
            const float Wi = (float)WxL[(size_t)rr * 1024 + 256 + col];
            const float Wu = (float)WxL[(size_t)rr * 1024 + 512 + col];
            const float Wo = (float)WxL[(size_t)rr * 1024 + 768 + col];
            const float ba = bfaL[(size_t)rr * 256 + col];
            const float ig = sigmoidf_((float)iuoL[(size_t)rr * 768 + col] + Wi);
            const float ug = tanhf((float)iuoL[(size_t)rr * 768 + 256 + col] + Wu);
            const float og = sigmoidf_((float)iuoL[(size_t)rr * 768 + 512 + col] + Wo);
            const float nc = fmaf(ig, ug, ba);
            const float nh = og * tanhf(nc);
            char* rowN = Snext + (size_t)g * SROW;
            ((float*)rowN)[col] = nc;
            const bf16_t nhb = (bf16_t)nh;
            ((bf16_t*)(rowN + 1024))[col] = nhb;
            const int ss2 = ((col >> 3) + 4 * (rr & 7)) & 31;
            hsumL[(size_t)rr * 256 + ss2 * 8 + (col & 7)] = nhb;
        }
    }

    if (l < LL - 1) {
        __syncthreads();
        // ---- phase 5: Hf_next = h_next @ UfW + Ufb (wave w -> tiles 2w, 2w+1) ----
        const int ct0 = 2 * w;
        const bf16_t* bq0 = UfWt + (size_t)(ct0 * 16 + r) * HH + kg * 8;
        const bf16_t* bq1 = bq0 + (size_t)16 * HH;
        f32x4 ac0 = zero, ac1 = zero;
        for (int k0 = 0; k0 < HH; k0 += 32) {
            const int ss = (((k0 >> 3) + kg) + 4 * (r & 7)) & 31;
            const bf16x8 a = *(const bf16x8*)(hsumL + (size_t)r * 256 + ss * 8);
            const bf16x8 b0 = *(const bf16x8*)bq0;
            const bf16x8 b1 = *(const bf16x8*)bq1;
            ac0 = __builtin_amdgcn_mfma_f32_16x16x32_bf16(a, b0, ac0, 0, 0, 0);
            ac1 = __builtin_amdgcn_mfma_f32_16x16x32_bf16(a, b1, ac1, 0, 0, 0);
            bq0 += 32; bq1 += 32;
        }
        const int c0 = ct0 * 16 + r, c1 = c0 + 16;
        const float bv0 = Ufb[c0], bv1 = Ufb[c1];
        #pragma unroll
        for (int jj = 0; jj < 4; ++jj) {
            bf16_t* fr = (bf16_t*)(Snext + (size_t)(g0 + kg * 4 + jj) * SROW + 1536);
            fr[c0] = (bf16_t)(ac0[jj] + bv0);
            fr[c1] = (bf16_t)(ac1[jj] + bv1);
        }
    }
}

// ---------------- siamese head (h read from packed state) ----------------
__global__ __launch_bounds__(256) void k_final(
    const char* __restrict__ Sfin, const bf16_t* __restrict__ xbf,
    const float* __restrict__ dW, const float* __restrict__ db,
    const float* __restrict__ oW, const float* __restrict__ ob,
    float* __restrict__ out)
{
    __shared__ __align__(16) float ad[8][HH];
    __shared__ __align__(16) float xx[8][512];
    const int t = threadIdx.x;
    const int n0 = blockIdx.x * 8;
    const size_t xoff1 = (size_t)(LL - 1) * NN * HH;
    const size_t xoff2 = (size_t)LN * HH + xoff1;
    #pragma unroll
    for (int rr = 0; rr < 8; ++rr) {
        const int n = n0 + rr;
        const float h1 = (float)((const bf16_t*)(Sfin + (size_t)n * SROW + 1024))[t]
                       + (float)xbf[xoff1 + (size_t)n * HH + t];
        const float h2 = (float)((const bf16_t*)(Sfin + (size_t)(NN + n) * SROW + 1024))[t]
                       + (float)xbf[xoff2 + (size_t)n * HH + t];
        ad[rr][t] = fabsf(h1 - h2);
    }
    __syncthreads();
    float a0[8], a1[8];
    #pragma unroll
    for (int rr = 0; rr < 8; ++rr) { a0[rr] = 0.f; a1[rr] = 0.f; }
    for (int k = 0; k < HH; k += 4) {
        #pragma unroll
        for (int kk = 0; kk < 4; ++kk) {
            const float b0 = dW[(size_t)(k + kk) * 512 + t];
            const float b1 = dW[(size_t)(k + kk) * 512 + 256 + t];
            #pragma unroll
            for (int rr = 0; rr < 8; ++rr) {
                const float av = ad[rr][k + kk];
                a0[rr] = fmaf(av, b0, a0[rr]);
                a1[rr] = fmaf(av, b1, a1[rr]);
            }
        }
    }
    const float db0 = db[t], db1 = db[256 + t];
    #pragma unroll
    for (int rr = 0; rr < 8; ++rr) {
        xx[rr][t] = tanhf(a0[rr] + db0);
        xx[rr][256 + t] = tanhf(a1[rr] + db1);
    }
    __syncthreads();
    const int w = t >> 6, lane = t & 63;
    for (int rr = w; rr < 8; rr += 4) {
        float p0 = 0.f, p1 = 0.f;
        for (int k = lane; k < 512; k += 64) {
            const float xv = xx[rr][k];
            p0 = fmaf(xv, oW[2 * k + 0], p0);
            p1 = fmaf(xv, oW[2 * k + 1], p1);
        }
        #pragma unroll
        for (int off = 32; off > 0; off >>= 1) {
            p0 += __shfl_down(p0, off);
            p1 += __shfl_down(p1, off);
        }
        if (lane == 0) {
            const float l0 = p0 + ob[0], l1 = p1 + ob[1];
            const float mx = fmaxf(l0, l1);
            const float e0 = expf(l0 - mx), e1 = expf(l1 - mx);
            const float inv = 1.f / (e0 + e1);
            out[(size_t)(n0 + rr) * 2 + 0] = e0 * inv;
            out[(size_t)(n0 + rr) * 2 + 1] = e1 * inv;
        }
    }
}

extern "C" void kernel_launch(void* const* d_in, const int* in_sizes, int n_in,
                              void* d_out, int out_size, void* d_ws, size_t ws_size,
                              hipStream_t stream) {
    (void)in_sizes; (void)n_in; (void)out_size; (void)ws_size;
    const int*   tok1 = (const int*)d_in[0];
    const int*   idx1 = (const int*)d_in[1];
    const int*   tok2 = (const int*)d_in[2];
    const int*   idx2 = (const int*)d_in[3];
    const float* E    = (const float*)d_in[4];
    const float* linW = (const float*)d_in[5];
    const float* linb = (const float*)d_in[6];
    const float* UfW  = (const float*)d_in[7];
    const float* Ufb  = (const float*)d_in[8];
    const float* UiW  = (const float*)d_in[9];
    const float* Uib  = (const float*)d_in[10];
    const float* WW   = (const float*)d_in[11];
    const float* Wb   = (const float*)d_in[12];
    const float* dW   = (const float*)d_in[13];
    const float* db   = (const float*)d_in[14];
    const float* oW   = (const float*)d_in[15];
    const float* ob   = (const float*)d_in[16];
    float* out = (float*)d_out;

    // ws: xbf | UNION{ Ebf (dead after embed) | SA SB packed state } | weights  (~52.3 MB)
    bf16_t* xbf = (bf16_t*)d_ws;                        // 12,582,912 elems (25,165,824 B)
    char*   uni = (char*)(xbf + (size_t)12582912);
    bf16_t* Ebf = (bf16_t*)uni;                         // 25.6 MB
    char*   SA  = uni;                                  // 4097 rows x 2048 B = 8,390,656 B
    char*   SB  = uni + 8390656;                        // total 16.78 MB < 25.6 MB
    bf16_t* linWt = (bf16_t*)(uni + 25600000);          // 262,144
    bf16_t* WWt   = linWt + (size_t)262144;             // 262,144
    bf16_t* UfWt  = WWt   + (size_t)262144;             // 65,536
    bf16_t* UiWt  = UfWt  + (size_t)65536;              // 196,608

    k_cvtE<<<2048, 256, 0, stream>>>(E, Ebf, VV * HH / 4);
    k_cvtW<<<3072, 256, 0, stream>>>(linW, WW, UfW, UiW, linWt, WWt, UfWt, UiWt);

    k_embed<<<768, 256, 0, stream>>>(tok1, tok2, Ebf, linWt, linb, xbf);

    // zero dummy rows AFTER embed (SA/SB alias the Ebf region)
    k_zero<<<1, 256, 0, stream>>>((float*)SA, (float*)SB);

    char *Sp = SA, *Sn = SB;
    for (int l = 0; l < LL; ++l) {
        // l==0: idx[0] all -1 -> all children = ZROW (zeroed) -> poison/alias safe
        k_step<<<256, 512, 0, stream>>>(xbf, idx1, idx2, l,
                                        UfWt, Ufb, UiWt, Uib, WWt, Wb, Sp, Sn);
        char* ts = Sp; Sp = Sn; Sn = ts;
    }

    k_final<<<NN / 8, 256, 0, stream>>>(Sp, xbf, dW, db, oW, ob, out);
}